// Round 1
// baseline (1952.331 us; speedup 1.0000x reference)
//
#include <hip/hip_runtime.h>
#include <hip/hip_bf16.h>
#include <math.h>

#define N_ROWS 131072
#define DIM 512
#define HID 1024
#define MEMC 512

typedef __attribute__((ext_vector_type(8))) short bf16x8;
typedef __attribute__((ext_vector_type(4))) float f32x4;

// ---------------------------------------------------------------------------
// Prep: cast weights to bf16 (transposed to [out_col][k] = B^T, K-contiguous)
// ---------------------------------------------------------------------------
__global__ void prep_weights(const float* __restrict__ up_w,   // [DIM][HID]
                             const float* __restrict__ down_w, // [HID][DIM]
                             const float* __restrict__ mb,     // [MEMC][DIM]
                             __hip_bfloat16* __restrict__ wtup, // [HID][DIM]
                             __hip_bfloat16* __restrict__ wtdn, // [DIM][HID]
                             __hip_bfloat16* __restrict__ cb)   // [MEMC][DIM]
{
    int i = blockIdx.x * blockDim.x + threadIdx.x;
    const int UP = DIM * HID;
    const int DN = HID * DIM;
    const int CB = MEMC * DIM;
    if (i < UP) {
        int n = i / DIM, k = i % DIM;              // wtup[n][k] = up_w[k][n]
        wtup[i] = __float2bfloat16(up_w[k * HID + n]);
    } else if (i < UP + DN) {
        int j = i - UP;
        int n = j / HID, k = j % HID;              // wtdn[n][k] = down_w[k][n]
        wtdn[j] = __float2bfloat16(down_w[k * DIM + n]);
    } else if (i < UP + DN + CB) {
        int j = i - UP - DN;
        cb[j] = __float2bfloat16(mb[j]);
    }
}

// ||c||^2 per code, one wave per code
__global__ void code_norms(const float* __restrict__ mb, float* __restrict__ cnorm)
{
    int wave = (blockIdx.x * blockDim.x + threadIdx.x) >> 6;
    int lane = threadIdx.x & 63;
    if (wave >= MEMC) return;
    float s = 0.f;
    #pragma unroll
    for (int t = 0; t < DIM / 64; ++t) {
        float v = mb[(size_t)wave * DIM + t * 64 + lane];
        s += v * v;
    }
    #pragma unroll
    for (int off = 32; off > 0; off >>= 1) s += __shfl_down(s, off);
    if (lane == 0) cnorm[wave] = s;
}

// ---------------------------------------------------------------------------
// x = input_emb + 0.1*neighbors + state_mu  -> x_f32 and x_bf16
// ---------------------------------------------------------------------------
__global__ void make_x(const float4* __restrict__ emb, const float4* __restrict__ nbr,
                       const float4* __restrict__ mu, float4* __restrict__ xf,
                       uint2* __restrict__ xb)
{
    int i = blockIdx.x * blockDim.x + threadIdx.x;  // over N*DIM/4
    float4 e = emb[i], n = nbr[i], m = mu[i & (DIM / 4 - 1)];
    float4 x;
    x.x = e.x + 0.1f * n.x + m.x;
    x.y = e.y + 0.1f * n.y + m.y;
    x.z = e.z + 0.1f * n.z + m.z;
    x.w = e.w + 0.1f * n.w + m.w;
    xf[i] = x;
    union { __hip_bfloat16 h[4]; uint2 u; } p;
    p.h[0] = __float2bfloat16(x.x); p.h[1] = __float2bfloat16(x.y);
    p.h[2] = __float2bfloat16(x.z); p.h[3] = __float2bfloat16(x.w);
    xb[i] = p.u;
}

// ---------------------------------------------------------------------------
// Tiled MFMA GEMM:  C[M][NC] = A[M][K] @ B[NC][K]^T   (bf16 in, f32 acc)
// 128x128 block, 4 waves (2x2), each wave 4x4 tiles of 16x16x32 MFMA.
// MODE 1: outb = bf16(silu(acc + bias))                  (h)
// MODE 2: v = resid + (acc + bias)*tanh(gate); outf=v, outb=bf16(v)  (x2)
// ---------------------------------------------------------------------------
#define BM 128
#define BN 128
#define BK 32

template <int MODE>
__global__ __launch_bounds__(256)
void gemm_bt(const __hip_bfloat16* __restrict__ A,
             const __hip_bfloat16* __restrict__ B,
             int M, int NC, int K,
             const float* __restrict__ bias,
             const float* resid,          // may alias outf (MODE 2)
             const float* __restrict__ gate,
             float* outf,
             __hip_bfloat16* __restrict__ outb)
{
    __shared__ __align__(16) __hip_bfloat16 As[BM * BK];
    __shared__ __align__(16) __hip_bfloat16 Bs[BN * BK];

    const int tid  = threadIdx.x;
    const int w    = tid >> 6;
    const int lane = tid & 63;
    const int quad = lane >> 4;
    const int l16  = lane & 15;
    const int wrow = w >> 1, wcol = w & 1;

    const int rowA0 = blockIdx.y * BM;
    const int rowB0 = blockIdx.x * BN;

    f32x4 acc[4][4];
    #pragma unroll
    for (int i = 0; i < 4; ++i)
        #pragma unroll
        for (int j = 0; j < 4; ++j)
            acc[i][j] = (f32x4){0.f, 0.f, 0.f, 0.f};

    const int kTiles = K / BK;
    for (int kt = 0; kt < kTiles; ++kt) {
        const int k0 = kt * BK;
        #pragma unroll
        for (int c = 0; c < 2; ++c) {
            int chunk = w * 2 + c;              // 0..7, each covers 1KB of tile
            int flat  = chunk * 512;            // element offset of chunk base
            int lflat = flat + lane * 8;        // this lane's 8 elements
            int row   = lflat >> 5;             // tile row (32 elem per row)
            int col   = lflat & 31;
            __builtin_amdgcn_global_load_lds(
                (const __attribute__((address_space(1))) void*)(A + (size_t)(rowA0 + row) * K + k0 + col),
                (__attribute__((address_space(3))) void*)(As + flat),
                16, 0, 0);
            __builtin_amdgcn_global_load_lds(
                (const __attribute__((address_space(1))) void*)(B + (size_t)(rowB0 + row) * K + k0 + col),
                (__attribute__((address_space(3))) void*)(Bs + flat),
                16, 0, 0);
        }
        __syncthreads();   // drains vmcnt before barrier -> LDS tiles ready

        bf16x8 av[4], bv[4];
        #pragma unroll
        for (int i = 0; i < 4; ++i)
            av[i] = *(const bf16x8*)&As[(wrow * 64 + i * 16 + l16) * BK + quad * 8];
        #pragma unroll
        for (int j = 0; j < 4; ++j)
            bv[j] = *(const bf16x8*)&Bs[(wcol * 64 + j * 16 + l16) * BK + quad * 8];
        #pragma unroll
        for (int i = 0; i < 4; ++i)
            #pragma unroll
            for (int j = 0; j < 4; ++j)
                acc[i][j] = __builtin_amdgcn_mfma_f32_16x16x32_bf16(av[i], bv[j], acc[i][j], 0, 0, 0);
        __syncthreads();   // all waves done reading LDS before next stage
    }

    float tg = 0.f;
    if (MODE == 2) tg = tanhf(gate[0]);

    #pragma unroll
    for (int i = 0; i < 4; ++i) {
        #pragma unroll
        for (int j = 0; j < 4; ++j) {
            #pragma unroll
            for (int r = 0; r < 4; ++r) {
                int grow = rowA0 + wrow * 64 + i * 16 + quad * 4 + r;
                int gcol = rowB0 + wcol * 64 + j * 16 + l16;
                float v = acc[i][j][r];
                size_t oidx = (size_t)grow * NC + gcol;
                if (MODE == 1) {
                    v += bias[gcol];
                    v = v / (1.f + expf(-v));          // silu
                    outb[oidx] = __float2bfloat16(v);
                } else if (MODE == 2) {
                    v = resid[oidx] + (v + bias[gcol]) * tg;
                    outf[oidx] = v;
                    outb[oidx] = __float2bfloat16(v);
                }
            }
        }
    }
}

// ---------------------------------------------------------------------------
// Fused VQ: scores GEMM (x2 @ C^T) + per-row argmin + gather + nan_to_num +
// norm clamp, never materializing the [N][MEMC] score matrix.
// Block = 32 rows x ALL 512 codes. 4 waves; wave w owns codes [w*128, w*128+128).
// A (x2 bf16) staged in LDS with padded rows (one global_load_lds per row, so
// padding doesn't break the wave-uniform-dest rule). B (codebook, 512 KB)
// read per-fragment straight from global: L2-resident across all blocks.
// acc: 2x8 f32x4 = 64 VGPR/lane (rows i*16+quad*4+r, codes w*128+j*16+l16).
// No barriers inside the k-loop (A tile is read-only after the first barrier).
// ---------------------------------------------------------------------------
#define VQ_RB 32
#define VQ_PAD_K 536   // 512 + 24: row stride 1072 B (16B-aligned, bank-spread)

__global__ __launch_bounds__(256)
void vq_final(const __hip_bfloat16* __restrict__ xb,   // [N][DIM] bf16 of x2
              const __hip_bfloat16* __restrict__ cb,   // [MEMC][DIM] bf16
              const float* __restrict__ cnorm,         // [MEMC]
              const float* __restrict__ x2,            // [N][DIM] f32
              const float* __restrict__ mb,            // [MEMC][DIM] f32
              float* __restrict__ out)                 // [N][DIM]
{
    __shared__ __align__(16) __hip_bfloat16 Abf[VQ_RB][VQ_PAD_K];
    __shared__ float sbest[4][VQ_RB];
    __shared__ int   sidx[4][VQ_RB];
    __shared__ int   fidx[VQ_RB];

    const int tid  = threadIdx.x;
    const int w    = tid >> 6;
    const int lane = tid & 63;
    const int quad = lane >> 4;
    const int l16  = lane & 15;
    const int row0 = blockIdx.x * VQ_RB;

    // Stage A tile: one gld call per row (64 lanes x 16B = full 1KB row).
    #pragma unroll
    for (int r8 = 0; r8 < 8; ++r8) {
        int r = w * 8 + r8;
        __builtin_amdgcn_global_load_lds(
            (const __attribute__((address_space(1))) void*)(xb + (size_t)(row0 + r) * DIM + lane * 8),
            (__attribute__((address_space(3))) void*)(&Abf[r][0]),
            16, 0, 0);
    }

    f32x4 acc[2][8];
    #pragma unroll
    for (int i = 0; i < 2; ++i)
        #pragma unroll
        for (int j = 0; j < 8; ++j)
            acc[i][j] = (f32x4){0.f, 0.f, 0.f, 0.f};

    __syncthreads();   // drains vmcnt -> A tile ready; only barrier before epi

    // B fragment base for this lane: code (w*128 + j*16 + l16), k = kt*32+quad*8
    const __hip_bfloat16* bbase = cb + (size_t)(w * 128 + l16) * DIM + quad * 8;

    for (int kt = 0; kt < DIM / 32; ++kt) {
        bf16x8 bv[8];
        #pragma unroll
        for (int j = 0; j < 8; ++j)
            bv[j] = *(const bf16x8*)(bbase + (size_t)j * 16 * DIM + kt * 32);
        bf16x8 a0 = *(const bf16x8*)&Abf[l16][kt * 32 + quad * 8];
        bf16x8 a1 = *(const bf16x8*)&Abf[16 + l16][kt * 32 + quad * 8];
        #pragma unroll
        for (int j = 0; j < 8; ++j) {
            acc[0][j] = __builtin_amdgcn_mfma_f32_16x16x32_bf16(a0, bv[j], acc[0][j], 0, 0, 0);
            acc[1][j] = __builtin_amdgcn_mfma_f32_16x16x32_bf16(a1, bv[j], acc[1][j], 0, 0, 0);
        }
    }

    // Per-lane argmin over j (codes j*16+l16), then butterfly over l16.
    float cn[8];
    #pragma unroll
    for (int j = 0; j < 8; ++j) cn[j] = cnorm[w * 128 + j * 16 + l16];

    #pragma unroll
    for (int i = 0; i < 2; ++i) {
        #pragma unroll
        for (int r = 0; r < 4; ++r) {
            float b = INFINITY; int bi = 0x7fffffff;
            #pragma unroll
            for (int j = 0; j < 8; ++j) {
                float s = -2.f * acc[i][j][r] + cn[j];   // same expr as before
                int c = w * 128 + j * 16 + l16;
                if (s < b || (s == b && c < bi)) { b = s; bi = c; }
            }
            #pragma unroll
            for (int m = 1; m <= 8; m <<= 1) {
                float ob = __shfl_xor(b, m);
                int   oi = __shfl_xor(bi, m);
                if (ob < b || (ob == b && oi < bi)) { b = ob; bi = oi; }
            }
            if (l16 == 0) {
                int row = i * 16 + quad * 4 + r;
                sbest[w][row] = b; sidx[w][row] = bi;
            }
        }
    }
    __syncthreads();

    // Cross-wave combine (waves ascending = code index ascending).
    if (tid < VQ_RB) {
        float b = sbest[0][tid]; int bi = sidx[0][tid];
        #pragma unroll
        for (int w2 = 1; w2 < 4; ++w2) {
            float ob = sbest[w2][tid]; int oi = sidx[w2][tid];
            if (ob < b || (ob == b && oi < bi)) { b = ob; bi = oi; }
        }
        fidx[tid] = bi;
    }
    __syncthreads();

    // Gather + nan_to_num + norm clamp; wave w handles rows w*8..w*8+7.
    #pragma unroll
    for (int r8 = 0; r8 < 8; ++r8) {
        int row = w * 8 + r8;
        const float* cp = mb + (size_t)fidx[row] * DIM;
        const float* xp = x2 + (size_t)(row0 + row) * DIM;
        float v[DIM / 64]; float ss = 0.f;
        #pragma unroll
        for (int t = 0; t < DIM / 64; ++t) {
            float x = xp[t * 64 + lane] + 0.05f * cp[t * 64 + lane];
            if (x != x) x = 0.f;
            else if (x == INFINITY) x = 1.f;
            else if (x == -INFINITY) x = -1.f;
            v[t] = x; ss += x * x;
        }
        #pragma unroll
        for (int off = 32; off > 0; off >>= 1) ss += __shfl_xor(ss, off);
        float nrm = sqrtf(ss);
        float scale = (nrm > 10.f) ? (10.f / fmaxf(nrm, 1e-6f)) : 1.f;
        float* op = out + (size_t)(row0 + row) * DIM;
        #pragma unroll
        for (int t = 0; t < DIM / 64; ++t)
            op[t * 64 + lane] = v[t] * scale;
    }
}

// ---------------------------------------------------------------------------
extern "C" void kernel_launch(void* const* d_in, const int* in_sizes, int n_in,
                              void* d_out, int out_size, void* d_ws, size_t ws_size,
                              hipStream_t stream)
{
    const float* input_emb = (const float*)d_in[0];
    const float* neighbors = (const float*)d_in[1];
    const float* state_mu  = (const float*)d_in[2];
    const float* up_w      = (const float*)d_in[3];
    const float* up_b      = (const float*)d_in[4];
    const float* down_w    = (const float*)d_in[5];
    const float* down_b    = (const float*)d_in[6];
    const float* gate      = (const float*)d_in[7];
    const float* mbook     = (const float*)d_in[8];
    float* out = (float*)d_out;

    char* w = (char*)d_ws;
    size_t off = 0;
    float* x_f32 = (float*)(w + off);                 // x, then x2 (in-place)
    off += (size_t)N_ROWS * DIM * 4;                  // 268 MB
    __hip_bfloat16* xb = (__hip_bfloat16*)(w + off);  // x bf16, then x2 bf16
    off += (size_t)N_ROWS * DIM * 2;                  // 134 MB
    __hip_bfloat16* h_bf16 = (__hip_bfloat16*)(w + off);
    off += (size_t)N_ROWS * HID * 2;                  // 268 MB
    __hip_bfloat16* wtup = (__hip_bfloat16*)(w + off); off += (size_t)HID * DIM * 2;
    __hip_bfloat16* wtdn = (__hip_bfloat16*)(w + off); off += (size_t)DIM * HID * 2;
    __hip_bfloat16* cb   = (__hip_bfloat16*)(w + off); off += (size_t)MEMC * DIM * 2;
    float* cnorm = (float*)(w + off);                  off += MEMC * 4;

    prep_weights<<<(DIM * HID + HID * DIM + MEMC * DIM + 255) / 256, 256, 0, stream>>>(
        up_w, down_w, mbook, wtup, wtdn, cb);
    code_norms<<<MEMC * 64 / 256, 256, 0, stream>>>(mbook, cnorm);
    make_x<<<(N_ROWS * DIM / 4) / 256, 256, 0, stream>>>(
        (const float4*)input_emb, (const float4*)neighbors, (const float4*)state_mu,
        (float4*)x_f32, (uint2*)xb);

    // h = silu(x @ W_up + b_up)           [N][HID] bf16
    gemm_bt<1><<<dim3(HID / BN, N_ROWS / BM), 256, 0, stream>>>(
        xb, wtup, N_ROWS, HID, DIM, up_b, nullptr, nullptr, nullptr, h_bf16);
    // x2 = x + (h @ W_down + b_down)*tanh(gate)   (f32 in-place + bf16)
    gemm_bt<2><<<dim3(DIM / BN, N_ROWS / BM), 256, 0, stream>>>(
        h_bf16, wtdn, N_ROWS, DIM, HID, down_b, x_f32, gate, x_f32, xb);
    // Fused: scores = x2 @ C^T, argmin, gather, nan fix, norm clamp -> out
    vq_final<<<N_ROWS / VQ_RB, 256, 0, stream>>>(xb, cb, cnorm, x_f32, mbook, out);
}

// Round 2
// 1579.254 us; speedup vs baseline: 1.2362x; 1.2362x over previous
//
#include <hip/hip_runtime.h>
#include <hip/hip_bf16.h>
#include <math.h>

#define N_ROWS 131072
#define DIM 512
#define HID 1024
#define MEMC 512

typedef __attribute__((ext_vector_type(8))) short bf16x8;
typedef __attribute__((ext_vector_type(4))) float f32x4;

// ---------------------------------------------------------------------------
// Prep: cast weights to bf16 (transposed to [out_col][k] = B^T, K-contiguous)
// ---------------------------------------------------------------------------
__global__ void prep_weights(const float* __restrict__ up_w,   // [DIM][HID]
                             const float* __restrict__ down_w, // [HID][DIM]
                             const float* __restrict__ mb,     // [MEMC][DIM]
                             __hip_bfloat16* __restrict__ wtup, // [HID][DIM]
                             __hip_bfloat16* __restrict__ wtdn, // [DIM][HID]
                             __hip_bfloat16* __restrict__ cb)   // [MEMC][DIM]
{
    int i = blockIdx.x * blockDim.x + threadIdx.x;
    const int UP = DIM * HID;
    const int DN = HID * DIM;
    const int CB = MEMC * DIM;
    if (i < UP) {
        int n = i / DIM, k = i % DIM;              // wtup[n][k] = up_w[k][n]
        wtup[i] = __float2bfloat16(up_w[k * HID + n]);
    } else if (i < UP + DN) {
        int j = i - UP;
        int n = j / HID, k = j % HID;              // wtdn[n][k] = down_w[k][n]
        wtdn[j] = __float2bfloat16(down_w[k * DIM + n]);
    } else if (i < UP + DN + CB) {
        int j = i - UP - DN;
        cb[j] = __float2bfloat16(mb[j]);
    }
}

// ||c||^2 per code, one wave per code
__global__ void code_norms(const float* __restrict__ mb, float* __restrict__ cnorm)
{
    int wave = (blockIdx.x * blockDim.x + threadIdx.x) >> 6;
    int lane = threadIdx.x & 63;
    if (wave >= MEMC) return;
    float s = 0.f;
    #pragma unroll
    for (int t = 0; t < DIM / 64; ++t) {
        float v = mb[(size_t)wave * DIM + t * 64 + lane];
        s += v * v;
    }
    #pragma unroll
    for (int off = 32; off > 0; off >>= 1) s += __shfl_down(s, off);
    if (lane == 0) cnorm[wave] = s;
}

// ---------------------------------------------------------------------------
// x = input_emb + 0.1*neighbors + state_mu  -> x_f32 and x_bf16
// ---------------------------------------------------------------------------
__global__ void make_x(const float4* __restrict__ emb, const float4* __restrict__ nbr,
                       const float4* __restrict__ mu, float4* __restrict__ xf,
                       uint2* __restrict__ xb)
{
    int i = blockIdx.x * blockDim.x + threadIdx.x;  // over N*DIM/4
    float4 e = emb[i], n = nbr[i], m = mu[i & (DIM / 4 - 1)];
    float4 x;
    x.x = e.x + 0.1f * n.x + m.x;
    x.y = e.y + 0.1f * n.y + m.y;
    x.z = e.z + 0.1f * n.z + m.z;
    x.w = e.w + 0.1f * n.w + m.w;
    xf[i] = x;
    union { __hip_bfloat16 h[4]; uint2 u; } p;
    p.h[0] = __float2bfloat16(x.x); p.h[1] = __float2bfloat16(x.y);
    p.h[2] = __float2bfloat16(x.z); p.h[3] = __float2bfloat16(x.w);
    xb[i] = p.u;
}

// ---------------------------------------------------------------------------
// Tiled MFMA GEMM:  C[M][NC] = A[M][K] @ B[NC][K]^T   (bf16 in, f32 acc)
// 128x128 block, 4 waves (2x2), each wave 4x4 tiles of 16x16x32 MFMA.
// MODE 1: outb = bf16(silu(acc + bias))                  (h)
// MODE 2: v = resid + (acc + bias)*tanh(gate); outf=v, outb=bf16(v)  (x2)
// ---------------------------------------------------------------------------
#define BM 128
#define BN 128
#define BK 32

template <int MODE>
__global__ __launch_bounds__(256)
void gemm_bt(const __hip_bfloat16* __restrict__ A,
             const __hip_bfloat16* __restrict__ B,
             int M, int NC, int K,
             const float* __restrict__ bias,
             const float* resid,          // may alias outf (MODE 2)
             const float* __restrict__ gate,
             float* outf,
             __hip_bfloat16* __restrict__ outb)
{
    __shared__ __align__(16) __hip_bfloat16 As[BM * BK];
    __shared__ __align__(16) __hip_bfloat16 Bs[BN * BK];

    const int tid  = threadIdx.x;
    const int w    = tid >> 6;
    const int lane = tid & 63;
    const int quad = lane >> 4;
    const int l16  = lane & 15;
    const int wrow = w >> 1, wcol = w & 1;

    const int rowA0 = blockIdx.y * BM;
    const int rowB0 = blockIdx.x * BN;

    f32x4 acc[4][4];
    #pragma unroll
    for (int i = 0; i < 4; ++i)
        #pragma unroll
        for (int j = 0; j < 4; ++j)
            acc[i][j] = (f32x4){0.f, 0.f, 0.f, 0.f};

    const int kTiles = K / BK;
    for (int kt = 0; kt < kTiles; ++kt) {
        const int k0 = kt * BK;
        #pragma unroll
        for (int c = 0; c < 2; ++c) {
            int chunk = w * 2 + c;              // 0..7, each covers 1KB of tile
            int flat  = chunk * 512;            // element offset of chunk base
            int lflat = flat + lane * 8;        // this lane's 8 elements
            int row   = lflat >> 5;             // tile row (32 elem per row)
            int col   = lflat & 31;
            __builtin_amdgcn_global_load_lds(
                (const __attribute__((address_space(1))) void*)(A + (size_t)(rowA0 + row) * K + k0 + col),
                (__attribute__((address_space(3))) void*)(As + flat),
                16, 0, 0);
            __builtin_amdgcn_global_load_lds(
                (const __attribute__((address_space(1))) void*)(B + (size_t)(rowB0 + row) * K + k0 + col),
                (__attribute__((address_space(3))) void*)(Bs + flat),
                16, 0, 0);
        }
        __syncthreads();   // drains vmcnt before barrier -> LDS tiles ready

        bf16x8 av[4], bv[4];
        #pragma unroll
        for (int i = 0; i < 4; ++i)
            av[i] = *(const bf16x8*)&As[(wrow * 64 + i * 16 + l16) * BK + quad * 8];
        #pragma unroll
        for (int j = 0; j < 4; ++j)
            bv[j] = *(const bf16x8*)&Bs[(wcol * 64 + j * 16 + l16) * BK + quad * 8];
        #pragma unroll
        for (int i = 0; i < 4; ++i)
            #pragma unroll
            for (int j = 0; j < 4; ++j)
                acc[i][j] = __builtin_amdgcn_mfma_f32_16x16x32_bf16(av[i], bv[j], acc[i][j], 0, 0, 0);
        __syncthreads();   // all waves done reading LDS before next stage
    }

    float tg = 0.f;
    if (MODE == 2) tg = tanhf(gate[0]);

    #pragma unroll
    for (int i = 0; i < 4; ++i) {
        #pragma unroll
        for (int j = 0; j < 4; ++j) {
            #pragma unroll
            for (int r = 0; r < 4; ++r) {
                int grow = rowA0 + wrow * 64 + i * 16 + quad * 4 + r;
                int gcol = rowB0 + wcol * 64 + j * 16 + l16;
                float v = acc[i][j][r];
                size_t oidx = (size_t)grow * NC + gcol;
                if (MODE == 1) {
                    v += bias[gcol];
                    v = v / (1.f + expf(-v));          // silu
                    outb[oidx] = __float2bfloat16(v);
                } else if (MODE == 2) {
                    v = resid[oidx] + (v + bias[gcol]) * tg;
                    outf[oidx] = v;
                    outb[oidx] = __float2bfloat16(v);
                }
            }
        }
    }
}

// ---------------------------------------------------------------------------
// VQ scores + argmin -> fidx[N].  m97-style GEMM structure:
// BM=64 rows/block x all 512 codes, K=512, BK=32, 8 waves (512 thr).
// Wave w: rows (w>>2)*32..+32, codes (w&3)*128..+128 -> acc[2][8] (64 VGPR).
// Both A (xb rows) and B (codebook) staged per K-step via global_load_lds
// (coalesced, no VGPR round-trip) -- fixes round-1's per-lane global B loads
// that serialized on register pressure (4.7% MfmaUtil, 23% occupancy).
// Scores bit-identical to round-1 (same MFMA shapes, same kt order).
// ---------------------------------------------------------------------------
#define VQ_BM 64

__global__ __launch_bounds__(512, 4)
void vq_scores(const __hip_bfloat16* __restrict__ xb,   // [N][DIM] bf16 of x2
               const __hip_bfloat16* __restrict__ cb,   // [MEMC][DIM] bf16
               const float* __restrict__ cnorm,         // [MEMC]
               int* __restrict__ fidx)                  // [N]
{
    __shared__ __align__(16) __hip_bfloat16 As[VQ_BM * 32];   // 4 KB
    __shared__ __align__(16) __hip_bfloat16 Bs[MEMC * 32];    // 32 KB
    __shared__ float sbest[4][VQ_BM];
    __shared__ int   sidx[4][VQ_BM];

    const int tid  = threadIdx.x;
    const int w    = tid >> 6;
    const int lane = tid & 63;
    const int quad = lane >> 4;
    const int l16  = lane & 15;
    const int wr   = w >> 2;     // 0..1: row group
    const int wc   = w & 3;      // 0..3: code group
    const int row0 = blockIdx.x * VQ_BM;

    f32x4 acc[2][8];
    #pragma unroll
    for (int i = 0; i < 2; ++i)
        #pragma unroll
        for (int j = 0; j < 8; ++j)
            acc[i][j] = (f32x4){0.f, 0.f, 0.f, 0.f};

    for (int kt = 0; kt < DIM / 32; ++kt) {
        const int k0 = kt * 32;
        // Stage A tile [64][32]: waves 0..3, one 16B op per lane.
        if (w < 4) {
            int felem = w * 512 + lane * 8;
            int row = felem >> 5, col = felem & 31;
            __builtin_amdgcn_global_load_lds(
                (const __attribute__((address_space(1))) void*)(xb + (size_t)(row0 + row) * DIM + k0 + col),
                (__attribute__((address_space(3))) void*)(As + felem),
                16, 0, 0);
        }
        // Stage B tile [512][32]: all waves, 4 chunks of 16B per lane.
        #pragma unroll
        for (int c = 0; c < 4; ++c) {
            int felem = c * 4096 + w * 512 + lane * 8;
            int row = felem >> 5, col = felem & 31;
            __builtin_amdgcn_global_load_lds(
                (const __attribute__((address_space(1))) void*)(cb + (size_t)row * DIM + k0 + col),
                (__attribute__((address_space(3))) void*)(Bs + felem),
                16, 0, 0);
        }
        __syncthreads();   // drains vmcnt -> tiles ready

        bf16x8 av[2];
        #pragma unroll
        for (int i = 0; i < 2; ++i)
            av[i] = *(const bf16x8*)&As[(wr * 32 + i * 16 + l16) * 32 + quad * 8];
        // Two halves of 4 codes: keeps live bv at 16 VGPR (fits 128-cap).
        #pragma unroll
        for (int h = 0; h < 2; ++h) {
            bf16x8 bv[4];
            #pragma unroll
            for (int jj = 0; jj < 4; ++jj)
                bv[jj] = *(const bf16x8*)&Bs[(wc * 128 + (h * 4 + jj) * 16 + l16) * 32 + quad * 8];
            #pragma unroll
            for (int jj = 0; jj < 4; ++jj) {
                acc[0][h * 4 + jj] = __builtin_amdgcn_mfma_f32_16x16x32_bf16(av[0], bv[jj], acc[0][h * 4 + jj], 0, 0, 0);
                acc[1][h * 4 + jj] = __builtin_amdgcn_mfma_f32_16x16x32_bf16(av[1], bv[jj], acc[1][h * 4 + jj], 0, 0, 0);
            }
        }
        __syncthreads();   // all waves done reading before restage
    }

    // Per-lane argmin over this wave's 128-code slice, then l16 butterfly.
    float cn[8];
    #pragma unroll
    for (int j = 0; j < 8; ++j) cn[j] = cnorm[wc * 128 + j * 16 + l16];

    #pragma unroll
    for (int i = 0; i < 2; ++i) {
        #pragma unroll
        for (int r = 0; r < 4; ++r) {
            float b = INFINITY; int bi = 0x7fffffff;
            #pragma unroll
            for (int j = 0; j < 8; ++j) {
                float s = -2.f * acc[i][j][r] + cn[j];
                int c = wc * 128 + j * 16 + l16;
                if (s < b || (s == b && c < bi)) { b = s; bi = c; }
            }
            #pragma unroll
            for (int m = 1; m <= 8; m <<= 1) {
                float ob = __shfl_xor(b, m);
                int   oi = __shfl_xor(bi, m);
                if (ob < b || (ob == b && oi < bi)) { b = ob; bi = oi; }
            }
            if (l16 == 0) {
                int row = wr * 32 + i * 16 + quad * 4 + r;
                sbest[wc][row] = b; sidx[wc][row] = bi;
            }
        }
    }
    __syncthreads();

    // Cross-wave combine (code groups ascending => lowest-index tie-break).
    if (tid < VQ_BM) {
        float b = sbest[0][tid]; int bi = sidx[0][tid];
        #pragma unroll
        for (int g = 1; g < 4; ++g) {
            float ob = sbest[g][tid]; int oi = sidx[g][tid];
            if (ob < b || (ob == b && oi < bi)) { b = ob; bi = oi; }
        }
        fidx[row0 + tid] = bi;
    }
}

// ---------------------------------------------------------------------------
// Pure-BW epilogue: out = clamp_norm(nan_to_num(x2 + 0.05*mb[fidx])).
// 4 waves/block, one row per wave, float4 loads/stores.
// ---------------------------------------------------------------------------
__global__ __launch_bounds__(256)
void final_out(const int* __restrict__ fidx,
               const float* __restrict__ x2,    // [N][DIM]
               const float* __restrict__ mb,    // [MEMC][DIM] f32
               float* __restrict__ out)         // [N][DIM]
{
    int row  = blockIdx.x * 4 + (threadIdx.x >> 6);
    int lane = threadIdx.x & 63;
    int idx  = fidx[row];
    const float4* xp = (const float4*)(x2 + (size_t)row * DIM);
    const float4* cp = (const float4*)(mb + (size_t)idx * DIM);

    float4 v[2]; float ss = 0.f;
    #pragma unroll
    for (int t = 0; t < 2; ++t) {
        float4 a = xp[t * 64 + lane];
        float4 c = cp[t * 64 + lane];
        float e[4] = { a.x + 0.05f * c.x, a.y + 0.05f * c.y,
                       a.z + 0.05f * c.z, a.w + 0.05f * c.w };
        #pragma unroll
        for (int q = 0; q < 4; ++q) {
            float x = e[q];
            if (x != x) x = 0.f;
            else if (x == INFINITY) x = 1.f;
            else if (x == -INFINITY) x = -1.f;
            e[q] = x; ss += x * x;
        }
        v[t] = (float4){ e[0], e[1], e[2], e[3] };
    }
    #pragma unroll
    for (int off = 32; off > 0; off >>= 1) ss += __shfl_xor(ss, off);
    float nrm = sqrtf(ss);
    float scale = (nrm > 10.f) ? (10.f / fmaxf(nrm, 1e-6f)) : 1.f;
    float4* op = (float4*)(out + (size_t)row * DIM);
    #pragma unroll
    for (int t = 0; t < 2; ++t) {
        float4 x = v[t];
        op[t * 64 + lane] = (float4){ x.x * scale, x.y * scale, x.z * scale, x.w * scale };
    }
}

// ---------------------------------------------------------------------------
extern "C" void kernel_launch(void* const* d_in, const int* in_sizes, int n_in,
                              void* d_out, int out_size, void* d_ws, size_t ws_size,
                              hipStream_t stream)
{
    const float* input_emb = (const float*)d_in[0];
    const float* neighbors = (const float*)d_in[1];
    const float* state_mu  = (const float*)d_in[2];
    const float* up_w      = (const float*)d_in[3];
    const float* up_b      = (const float*)d_in[4];
    const float* down_w    = (const float*)d_in[5];
    const float* down_b    = (const float*)d_in[6];
    const float* gate      = (const float*)d_in[7];
    const float* mbook     = (const float*)d_in[8];
    float* out = (float*)d_out;

    char* w = (char*)d_ws;
    size_t off = 0;
    float* x_f32 = (float*)(w + off);                 // x, then x2 (in-place)
    off += (size_t)N_ROWS * DIM * 4;                  // 268 MB
    __hip_bfloat16* xb = (__hip_bfloat16*)(w + off);  // x bf16, then x2 bf16
    off += (size_t)N_ROWS * DIM * 2;                  // 134 MB
    __hip_bfloat16* h_bf16 = (__hip_bfloat16*)(w + off);
    off += (size_t)N_ROWS * HID * 2;                  // 268 MB
    __hip_bfloat16* wtup = (__hip_bfloat16*)(w + off); off += (size_t)HID * DIM * 2;
    __hip_bfloat16* wtdn = (__hip_bfloat16*)(w + off); off += (size_t)DIM * HID * 2;
    __hip_bfloat16* cb   = (__hip_bfloat16*)(w + off); off += (size_t)MEMC * DIM * 2;
    float* cnorm = (float*)(w + off);                  off += MEMC * 4;
    int* fidx    = (int*)(w + off);                    off += (size_t)N_ROWS * 4;

    prep_weights<<<(DIM * HID + HID * DIM + MEMC * DIM + 255) / 256, 256, 0, stream>>>(
        up_w, down_w, mbook, wtup, wtdn, cb);
    code_norms<<<MEMC * 64 / 256, 256, 0, stream>>>(mbook, cnorm);
    make_x<<<(N_ROWS * DIM / 4) / 256, 256, 0, stream>>>(
        (const float4*)input_emb, (const float4*)neighbors, (const float4*)state_mu,
        (float4*)x_f32, (uint2*)xb);

    // h = silu(x @ W_up + b_up)           [N][HID] bf16
    gemm_bt<1><<<dim3(HID / BN, N_ROWS / BM), 256, 0, stream>>>(
        xb, wtup, N_ROWS, HID, DIM, up_b, nullptr, nullptr, nullptr, h_bf16);
    // x2 = x + (h @ W_down + b_down)*tanh(gate)   (f32 in-place + bf16)
    gemm_bt<2><<<dim3(DIM / BN, N_ROWS / BM), 256, 0, stream>>>(
        h_bf16, wtdn, N_ROWS, DIM, HID, down_b, x_f32, gate, x_f32, xb);
    // scores + argmin -> fidx (scores never leave registers)
    vq_scores<<<N_ROWS / VQ_BM, 512, 0, stream>>>(xb, cb, cnorm, fidx);
    // gather + nan_to_num + norm clamp -> out
    final_out<<<N_ROWS / 4, 256, 0, stream>>>(fidx, x_f32, mbook, out);
}

// Round 3
// 1525.973 us; speedup vs baseline: 1.2794x; 1.0349x over previous
//
#include <hip/hip_runtime.h>
#include <hip/hip_bf16.h>
#include <math.h>

#define N_ROWS 131072
#define DIM 512
#define HID 1024
#define MEMC 512

typedef __attribute__((ext_vector_type(8))) short bf16x8;
typedef __attribute__((ext_vector_type(4))) float f32x4;

// ---------------------------------------------------------------------------
// Prep: cast weights to bf16 (transposed to [out_col][k] = B^T, K-contiguous)
// ---------------------------------------------------------------------------
__global__ void prep_weights(const float* __restrict__ up_w,   // [DIM][HID]
                             const float* __restrict__ down_w, // [HID][DIM]
                             const float* __restrict__ mb,     // [MEMC][DIM]
                             __hip_bfloat16* __restrict__ wtup, // [HID][DIM]
                             __hip_bfloat16* __restrict__ wtdn, // [DIM][HID]
                             __hip_bfloat16* __restrict__ cb)   // [MEMC][DIM]
{
    int i = blockIdx.x * blockDim.x + threadIdx.x;
    const int UP = DIM * HID;
    const int DN = HID * DIM;
    const int CB = MEMC * DIM;
    if (i < UP) {
        int n = i / DIM, k = i % DIM;              // wtup[n][k] = up_w[k][n]
        wtup[i] = __float2bfloat16(up_w[k * HID + n]);
    } else if (i < UP + DN) {
        int j = i - UP;
        int n = j / HID, k = j % HID;              // wtdn[n][k] = down_w[k][n]
        wtdn[j] = __float2bfloat16(down_w[k * DIM + n]);
    } else if (i < UP + DN + CB) {
        int j = i - UP - DN;
        cb[j] = __float2bfloat16(mb[j]);
    }
}

// ||c||^2 per code, one wave per code
__global__ void code_norms(const float* __restrict__ mb, float* __restrict__ cnorm)
{
    int wave = (blockIdx.x * blockDim.x + threadIdx.x) >> 6;
    int lane = threadIdx.x & 63;
    if (wave >= MEMC) return;
    float s = 0.f;
    #pragma unroll
    for (int t = 0; t < DIM / 64; ++t) {
        float v = mb[(size_t)wave * DIM + t * 64 + lane];
        s += v * v;
    }
    #pragma unroll
    for (int off = 32; off > 0; off >>= 1) s += __shfl_down(s, off);
    if (lane == 0) cnorm[wave] = s;
}

// ---------------------------------------------------------------------------
// x = input_emb + 0.1*neighbors + state_mu  -> x_f32 and x_bf16
// ---------------------------------------------------------------------------
__global__ void make_x(const float4* __restrict__ emb, const float4* __restrict__ nbr,
                       const float4* __restrict__ mu, float4* __restrict__ xf,
                       uint2* __restrict__ xb)
{
    int i = blockIdx.x * blockDim.x + threadIdx.x;  // over N*DIM/4
    float4 e = emb[i], n = nbr[i], m = mu[i & (DIM / 4 - 1)];
    float4 x;
    x.x = e.x + 0.1f * n.x + m.x;
    x.y = e.y + 0.1f * n.y + m.y;
    x.z = e.z + 0.1f * n.z + m.z;
    x.w = e.w + 0.1f * n.w + m.w;
    xf[i] = x;
    union { __hip_bfloat16 h[4]; uint2 u; } p;
    p.h[0] = __float2bfloat16(x.x); p.h[1] = __float2bfloat16(x.y);
    p.h[2] = __float2bfloat16(x.z); p.h[3] = __float2bfloat16(x.w);
    xb[i] = p.u;
}

// ---------------------------------------------------------------------------
// Tiled MFMA GEMM:  C[M][NC] = A[M][K] @ B[NC][K]^T   (bf16 in, f32 acc)
// 128x128 block, 4 waves (2x2), each wave 4x4 tiles of 16x16x32 MFMA.
// Double-buffered LDS + counted vmcnt (T3/T4 minimum form): tile kt+2 is
// staged into the buffer released after computing tile kt; top-of-iter wait
// is vmcnt(4) (own 4 ops of the current tile), never a full drain, so loads
// stay in flight across the raw s_barriers for a whole iteration.
// XCD-chunked block swizzle: same-A-panel blocks land on one XCD's L2.
// MODE 1: outb = bf16(silu(acc + bias))                  (h)
// MODE 2: v = resid + (acc + bias)*tanh(gate); outf=v, outb=bf16(v)  (x2)
// ---------------------------------------------------------------------------
#define BM 128
#define BN 128
#define BK 32

template <int MODE>
__global__ __launch_bounds__(256)
void gemm_bt(const __hip_bfloat16* __restrict__ A,
             const __hip_bfloat16* __restrict__ B,
             int M, int NC, int K,
             const float* __restrict__ bias,
             const float* resid,          // may alias outf (MODE 2)
             const float* __restrict__ gate,
             float* outf,
             __hip_bfloat16* __restrict__ outb)
{
    __shared__ __align__(16) __hip_bfloat16 As[2][BM * BK];
    __shared__ __align__(16) __hip_bfloat16 Bs[2][BN * BK];

    const int tid  = threadIdx.x;
    const int w    = tid >> 6;
    const int lane = tid & 63;
    const int quad = lane >> 4;
    const int l16  = lane & 15;
    const int wrow = w >> 1, wcol = w & 1;

    // Bijective XCD-chunked swizzle (nwg % 8 == 0 for both GEMMs here):
    // dispatch id lid goes to XCD lid%8; remap so each XCD owns a contiguous
    // chunk of row-panels -> A panel fetched into one L2, not eight.
    const int gx  = gridDim.x;
    const int nwg = gx * gridDim.y;
    const int lid = blockIdx.y * gx + blockIdx.x;
    const int swz = (lid & 7) * (nwg >> 3) + (lid >> 3);
    const int rowA0 = (swz / gx) * BM;
    const int rowB0 = (swz % gx) * BN;

    f32x4 acc[4][4];
    #pragma unroll
    for (int i = 0; i < 4; ++i)
        #pragma unroll
        for (int j = 0; j < 4; ++j)
            acc[i][j] = (f32x4){0.f, 0.f, 0.f, 0.f};

    // Stage one 128x32 A tile + B tile into buffer `buf` (4 gld ops / wave).
    auto stage = [&](int buf, int kt) {
        const int k0 = kt * BK;
        #pragma unroll
        for (int c = 0; c < 2; ++c) {
            int chunk = w * 2 + c;              // 0..7, each covers 1KB of tile
            int flat  = chunk * 512;            // element offset of chunk base
            int lflat = flat + lane * 8;        // this lane's 8 elements
            int row   = lflat >> 5;             // tile row (32 elem per row)
            int col   = lflat & 31;
            __builtin_amdgcn_global_load_lds(
                (const __attribute__((address_space(1))) void*)(A + (size_t)(rowA0 + row) * K + k0 + col),
                (__attribute__((address_space(3))) void*)(&As[buf][flat]),
                16, 0, 0);
            __builtin_amdgcn_global_load_lds(
                (const __attribute__((address_space(1))) void*)(B + (size_t)(rowB0 + row) * K + k0 + col),
                (__attribute__((address_space(3))) void*)(&Bs[buf][flat]),
                16, 0, 0);
        }
    };

    const int kTiles = K / BK;     // 16 (MODE 1) or 32 (MODE 2)
    stage(0, 0);
    stage(1, 1);
    int cur = 0;

    for (int kt = 0; kt < kTiles; ++kt) {
        // Wait for the CURRENT tile's 4 ops (oldest); keep next tile in flight.
        if (kt + 1 < kTiles) {
            asm volatile("s_waitcnt vmcnt(4)" ::: "memory");
        } else {
            asm volatile("s_waitcnt vmcnt(0)" ::: "memory");
        }
        __builtin_amdgcn_s_barrier();          // all waves' tile-kt loads landed
        __builtin_amdgcn_sched_barrier(0);     // no ds_read hoists above barrier

        bf16x8 av[4], bv[4];
        #pragma unroll
        for (int i = 0; i < 4; ++i)
            av[i] = *(const bf16x8*)&As[cur][(wrow * 64 + i * 16 + l16) * BK + quad * 8];
        #pragma unroll
        for (int j = 0; j < 4; ++j)
            bv[j] = *(const bf16x8*)&Bs[cur][(wcol * 64 + j * 16 + l16) * BK + quad * 8];
        #pragma unroll
        for (int i = 0; i < 4; ++i)
            #pragma unroll
            for (int j = 0; j < 4; ++j)
                acc[i][j] = __builtin_amdgcn_mfma_f32_16x16x32_bf16(av[i], bv[j], acc[i][j], 0, 0, 0);

        __builtin_amdgcn_sched_barrier(0);     // no ds_read sinks below barrier
        __builtin_amdgcn_s_barrier();          // all waves done reading buf cur
        __builtin_amdgcn_sched_barrier(0);
        if (kt + 2 < kTiles) stage(cur, kt + 2);   // reuse released buffer
        cur ^= 1;
    }

    float tg = 0.f;
    if (MODE == 2) tg = tanhf(gate[0]);

    #pragma unroll
    for (int i = 0; i < 4; ++i) {
        #pragma unroll
        for (int j = 0; j < 4; ++j) {
            #pragma unroll
            for (int r = 0; r < 4; ++r) {
                int grow = rowA0 + wrow * 64 + i * 16 + quad * 4 + r;
                int gcol = rowB0 + wcol * 64 + j * 16 + l16;
                float v = acc[i][j][r];
                size_t oidx = (size_t)grow * NC + gcol;
                if (MODE == 1) {
                    v += bias[gcol];
                    v = v / (1.f + expf(-v));          // silu
                    outb[oidx] = __float2bfloat16(v);
                } else if (MODE == 2) {
                    v = resid[oidx] + (v + bias[gcol]) * tg;
                    outf[oidx] = v;
                    outb[oidx] = __float2bfloat16(v);
                }
            }
        }
    }
}

// ---------------------------------------------------------------------------
// VQ scores + argmin -> fidx[N].  Same double-buffered counted-vmcnt
// structure as gemm_bt. BM=64 rows x all 512 codes, 8 waves.
// Waves 0..3 issue 5 gld ops/tile (1 A + 4 B); waves 4..7 issue 4 (B only),
// so the counted wait is vmcnt(5)/vmcnt(4) per wave group (wave-uniform).
// Scores bit-identical to round-2 (same MFMA shapes, same kt order).
// ---------------------------------------------------------------------------
#define VQ_BM 64

__global__ __launch_bounds__(512, 4)
void vq_scores(const __hip_bfloat16* __restrict__ xb,   // [N][DIM] bf16 of x2
               const __hip_bfloat16* __restrict__ cb,   // [MEMC][DIM] bf16
               const float* __restrict__ cnorm,         // [MEMC]
               int* __restrict__ fidx)                  // [N]
{
    __shared__ __align__(16) __hip_bfloat16 As[2][VQ_BM * 32];   // 2 x 4 KB
    __shared__ __align__(16) __hip_bfloat16 Bs[2][MEMC * 32];    // 2 x 32 KB
    __shared__ float sbest[4][VQ_BM];
    __shared__ int   sidx[4][VQ_BM];

    const int tid  = threadIdx.x;
    const int w    = tid >> 6;
    const int lane = tid & 63;
    const int quad = lane >> 4;
    const int l16  = lane & 15;
    const int wr   = w >> 2;     // 0..1: row group
    const int wc   = w & 3;      // 0..3: code group
    const int row0 = blockIdx.x * VQ_BM;

    f32x4 acc[2][8];
    #pragma unroll
    for (int i = 0; i < 2; ++i)
        #pragma unroll
        for (int j = 0; j < 8; ++j)
            acc[i][j] = (f32x4){0.f, 0.f, 0.f, 0.f};

    auto stage = [&](int buf, int kt) {
        const int k0 = kt * 32;
        // A tile [64][32]: waves 0..3, one 16B op per lane.
        if (w < 4) {
            int felem = w * 512 + lane * 8;
            int row = felem >> 5, col = felem & 31;
            __builtin_amdgcn_global_load_lds(
                (const __attribute__((address_space(1))) void*)(xb + (size_t)(row0 + row) * DIM + k0 + col),
                (__attribute__((address_space(3))) void*)(&As[buf][felem]),
                16, 0, 0);
        }
        // B tile [512][32]: all waves, 4 chunks of 16B per lane.
        #pragma unroll
        for (int c = 0; c < 4; ++c) {
            int felem = c * 4096 + w * 512 + lane * 8;
            int row = felem >> 5, col = felem & 31;
            __builtin_amdgcn_global_load_lds(
                (const __attribute__((address_space(1))) void*)(cb + (size_t)row * DIM + k0 + col),
                (__attribute__((address_space(3))) void*)(&Bs[buf][felem]),
                16, 0, 0);
        }
    };

    const int kTiles = DIM / 32;   // 16
    stage(0, 0);
    stage(1, 1);
    int cur = 0;

    for (int kt = 0; kt < kTiles; ++kt) {
        if (kt + 1 < kTiles) {
            if (w < 4) { asm volatile("s_waitcnt vmcnt(5)" ::: "memory"); }
            else       { asm volatile("s_waitcnt vmcnt(4)" ::: "memory"); }
        } else {
            asm volatile("s_waitcnt vmcnt(0)" ::: "memory");
        }
        __builtin_amdgcn_s_barrier();
        __builtin_amdgcn_sched_barrier(0);

        bf16x8 av[2];
        #pragma unroll
        for (int i = 0; i < 2; ++i)
            av[i] = *(const bf16x8*)&As[cur][(wr * 32 + i * 16 + l16) * 32 + quad * 8];
        // Two halves of 4 codes: keeps live bv at 16 VGPR.
        #pragma unroll
        for (int h = 0; h < 2; ++h) {
            bf16x8 bv[4];
            #pragma unroll
            for (int jj = 0; jj < 4; ++jj)
                bv[jj] = *(const bf16x8*)&Bs[cur][(wc * 128 + (h * 4 + jj) * 16 + l16) * 32 + quad * 8];
            #pragma unroll
            for (int jj = 0; jj < 4; ++jj) {
                acc[0][h * 4 + jj] = __builtin_amdgcn_mfma_f32_16x16x32_bf16(av[0], bv[jj], acc[0][h * 4 + jj], 0, 0, 0);
                acc[1][h * 4 + jj] = __builtin_amdgcn_mfma_f32_16x16x32_bf16(av[1], bv[jj], acc[1][h * 4 + jj], 0, 0, 0);
            }
        }

        __builtin_amdgcn_sched_barrier(0);
        __builtin_amdgcn_s_barrier();
        __builtin_amdgcn_sched_barrier(0);
        if (kt + 2 < kTiles) stage(cur, kt + 2);
        cur ^= 1;
    }

    // Per-lane argmin over this wave's 128-code slice, then l16 butterfly.
    float cn[8];
    #pragma unroll
    for (int j = 0; j < 8; ++j) cn[j] = cnorm[wc * 128 + j * 16 + l16];

    #pragma unroll
    for (int i = 0; i < 2; ++i) {
        #pragma unroll
        for (int r = 0; r < 4; ++r) {
            float b = INFINITY; int bi = 0x7fffffff;
            #pragma unroll
            for (int j = 0; j < 8; ++j) {
                float s = -2.f * acc[i][j][r] + cn[j];
                int c = wc * 128 + j * 16 + l16;
                if (s < b || (s == b && c < bi)) { b = s; bi = c; }
            }
            #pragma unroll
            for (int m = 1; m <= 8; m <<= 1) {
                float ob = __shfl_xor(b, m);
                int   oi = __shfl_xor(bi, m);
                if (ob < b || (ob == b && oi < bi)) { b = ob; bi = oi; }
            }
            if (l16 == 0) {
                int row = wr * 32 + i * 16 + quad * 4 + r;
                sbest[wc][row] = b; sidx[wc][row] = bi;
            }
        }
    }
    __syncthreads();

    // Cross-wave combine (code groups ascending => lowest-index tie-break).
    if (tid < VQ_BM) {
        float b = sbest[0][tid]; int bi = sidx[0][tid];
        #pragma unroll
        for (int g = 1; g < 4; ++g) {
            float ob = sbest[g][tid]; int oi = sidx[g][tid];
            if (ob < b || (ob == b && oi < bi)) { b = ob; bi = oi; }
        }
        fidx[row0 + tid] = bi;
    }
}

// ---------------------------------------------------------------------------
// Pure-BW epilogue: out = clamp_norm(nan_to_num(x2 + 0.05*mb[fidx])).
// 4 waves/block, one row per wave, float4 loads/stores.
// ---------------------------------------------------------------------------
__global__ __launch_bounds__(256)
void final_out(const int* __restrict__ fidx,
               const float* __restrict__ x2,    // [N][DIM]
               const float* __restrict__ mb,    // [MEMC][DIM] f32
               float* __restrict__ out)         // [N][DIM]
{
    int row  = blockIdx.x * 4 + (threadIdx.x >> 6);
    int lane = threadIdx.x & 63;
    int idx  = fidx[row];
    const float4* xp = (const float4*)(x2 + (size_t)row * DIM);
    const float4* cp = (const float4*)(mb + (size_t)idx * DIM);

    float4 v[2]; float ss = 0.f;
    #pragma unroll
    for (int t = 0; t < 2; ++t) {
        float4 a = xp[t * 64 + lane];
        float4 c = cp[t * 64 + lane];
        float e[4] = { a.x + 0.05f * c.x, a.y + 0.05f * c.y,
                       a.z + 0.05f * c.z, a.w + 0.05f * c.w };
        #pragma unroll
        for (int q = 0; q < 4; ++q) {
            float x = e[q];
            if (x != x) x = 0.f;
            else if (x == INFINITY) x = 1.f;
            else if (x == -INFINITY) x = -1.f;
            e[q] = x; ss += x * x;
        }
        v[t] = (float4){ e[0], e[1], e[2], e[3] };
    }
    #pragma unroll
    for (int off = 32; off > 0; off >>= 1) ss += __shfl_xor(ss, off);
    float nrm = sqrtf(ss);
    float scale = (nrm > 10.f) ? (10.f / fmaxf(nrm, 1e-6f)) : 1.f;
    float4* op = (float4*)(out + (size_t)row * DIM);
    #pragma unroll
    for (int t = 0; t < 2; ++t) {
        float4 x = v[t];
        op[t * 64 + lane] = (float4){ x.x * scale, x.y * scale, x.z * scale, x.w * scale };
    }
}

// ---------------------------------------------------------------------------
extern "C" void kernel_launch(void* const* d_in, const int* in_sizes, int n_in,
                              void* d_out, int out_size, void* d_ws, size_t ws_size,
                              hipStream_t stream)
{
    const float* input_emb = (const float*)d_in[0];
    const float* neighbors = (const float*)d_in[1];
    const float* state_mu  = (const float*)d_in[2];
    const float* up_w      = (const float*)d_in[3];
    const float* up_b      = (const float*)d_in[4];
    const float* down_w    = (const float*)d_in[5];
    const float* down_b    = (const float*)d_in[6];
    const float* gate      = (const float*)d_in[7];
    const float* mbook     = (const float*)d_in[8];
    float* out = (float*)d_out;

    char* w = (char*)d_ws;
    size_t off = 0;
    float* x_f32 = (float*)(w + off);                 // x, then x2 (in-place)
    off += (size_t)N_ROWS * DIM * 4;                  // 268 MB
    __hip_bfloat16* xb = (__hip_bfloat16*)(w + off);  // x bf16, then x2 bf16
    off += (size_t)N_ROWS * DIM * 2;                  // 134 MB
    __hip_bfloat16* h_bf16 = (__hip_bfloat16*)(w + off);
    off += (size_t)N_ROWS * HID * 2;                  // 268 MB
    __hip_bfloat16* wtup = (__hip_bfloat16*)(w + off); off += (size_t)HID * DIM * 2;
    __hip_bfloat16* wtdn = (__hip_bfloat16*)(w + off); off += (size_t)DIM * HID * 2;
    __hip_bfloat16* cb   = (__hip_bfloat16*)(w + off); off += (size_t)MEMC * DIM * 2;
    float* cnorm = (float*)(w + off);                  off += MEMC * 4;
    int* fidx    = (int*)(w + off);                    off += (size_t)N_ROWS * 4;

    prep_weights<<<(DIM * HID + HID * DIM + MEMC * DIM + 255) / 256, 256, 0, stream>>>(
        up_w, down_w, mbook, wtup, wtdn, cb);
    code_norms<<<MEMC * 64 / 256, 256, 0, stream>>>(mbook, cnorm);
    make_x<<<(N_ROWS * DIM / 4) / 256, 256, 0, stream>>>(
        (const float4*)input_emb, (const float4*)neighbors, (const float4*)state_mu,
        (float4*)x_f32, (uint2*)xb);

    // h = silu(x @ W_up + b_up)           [N][HID] bf16
    gemm_bt<1><<<dim3(HID / BN, N_ROWS / BM), 256, 0, stream>>>(
        xb, wtup, N_ROWS, HID, DIM, up_b, nullptr, nullptr, nullptr, h_bf16);
    // x2 = x + (h @ W_down + b_down)*tanh(gate)   (f32 in-place + bf16)
    gemm_bt<2><<<dim3(DIM / BN, N_ROWS / BM), 256, 0, stream>>>(
        h_bf16, wtdn, N_ROWS, DIM, HID, down_b, x_f32, gate, x_f32, xb);
    // scores + argmin -> fidx (scores never leave registers)
    vq_scores<<<N_ROWS / VQ_BM, 512, 0, stream>>>(xb, cb, cnorm, fidx);
    // gather + nan_to_num + norm clamp -> out
    final_out<<<N_ROWS / 4, 256, 0, stream>>>(fidx, x_f32, mbook, out);
}